// Round 1
// baseline (2403.363 us; speedup 1.0000x reference)
//
#include <hip/hip_runtime.h>

#define N 8192
#define D 64
#define B 2
#define KOUT 17
#define KSEL 20

// ---------------- kernel 1: squared norms sq[b][n] ----------------
__global__ void sq_kernel(const float* __restrict__ pc, float* __restrict__ sq) {
  int i = blockIdx.x * 256 + threadIdx.x;      // 0..16383
  int b = i >> 13, n = i & (N - 1);
  const float* g = pc + (size_t)b * D * N + n;
  float s = 0.f;
  #pragma unroll
  for (int d = 0; d < D; ++d) { float v = g[d * N]; s += v * v; }
  sq[i] = s;
}

// ---------------- kernel 2: fused f32 "GEMM" + per-row top-20 ----------------
// 512 blocks x 256 threads; block owns 32 rows of one batch, loops 64 col-tiles of 128.
__global__ __launch_bounds__(256, 2)
void knn_select_kernel(const float* __restrict__ pc, const float* __restrict__ sq,
                       int* __restrict__ cand) {
  __shared__ float Ar[32 * 64];       // swizzled [r][d]
  __shared__ float Ac[128 * 64];      // swizzled [c][d]   (reused as keybuf in merge)
  __shared__ float distb[32 * 168];   // keys [r][c], stride 168 (reused as idxbuf)

  int bx = blockIdx.x;                // 0..511
  int b = bx >> 8;
  int row0 = (bx & 255) << 5;
  const float* pcb = pc + (size_t)b * D * N;
  const float* sqb = sq + b * N;
  int t = threadIdx.x;
  const float INF = __builtin_inff();

  // stage Ar (32 rows x 64 d), element (r,d) -> Ar[r*64 + (d ^ (((r>>3)&7)<<2))]
  {
    int r = t & 31;
    int d0 = (t >> 5) * 8;
    int swz = ((r >> 3) & 7) << 2;
    #pragma unroll
    for (int i2 = 0; i2 < 8; ++i2) {
      int d = d0 + i2;
      Ar[r * 64 + (d ^ swz)] = pcb[d * N + row0 + r];
    }
  }

  float kd[KSEL]; int ki[KSEL];
  #pragma unroll
  for (int s = 0; s < KSEL; ++s) { kd[s] = INF; ki[s] = 0x7fffffff; }

  int tx = t & 31;          // col group: cols tx*4..+3
  int ty = t >> 5;          // row group: rows ty*4..+3 (0..7)
  int selrow = t >> 3;      // 0..31
  int selsub = t & 7;       // 16 cols each

  for (int tile = 0; tile < N / 128; ++tile) {
    int n0 = tile * 128;
    __syncthreads();
    // stage Ac (128 cols x 64 d), swizzled, via 4 coalesced scalar loads + ds_write_b128
    {
      int c = t & 127;
      int half = (t >> 7) & 1;
      int swz = ((c >> 3) & 7) << 2;
      const float* g = pcb + n0 + c;
      float* lb = Ac + c * 64;
      #pragma unroll
      for (int p = 0; p < 8; ++p) {
        int dbase = p * 8 + half * 4;
        float4 v;
        v.x = g[(size_t)(dbase + 0) * N];
        v.y = g[(size_t)(dbase + 1) * N];
        v.z = g[(size_t)(dbase + 2) * N];
        v.w = g[(size_t)(dbase + 3) * N];
        *(float4*)(lb + (dbase ^ swz)) = v;
      }
    }
    __syncthreads();

    // register-tiled dot products: 4 rows x 4 cols per lane
    float acc[4][4];
    #pragma unroll
    for (int i = 0; i < 4; ++i)
      #pragma unroll
      for (int j = 0; j < 4; ++j) acc[i][j] = 0.f;

    #pragma unroll
    for (int dd = 0; dd < 64; dd += 4) {
      float4 a[4], bv[4];
      #pragma unroll
      for (int i = 0; i < 4; ++i) {
        int r = ty * 4 + i;
        a[i] = *(const float4*)(Ar + r * 64 + (dd ^ (((r >> 3) & 7) << 2)));
      }
      #pragma unroll
      for (int j = 0; j < 4; ++j) {
        int c = tx * 4 + j;
        bv[j] = *(const float4*)(Ac + c * 64 + (dd ^ (((c >> 3) & 7) << 2)));
      }
      #pragma unroll
      for (int i = 0; i < 4; ++i)
        #pragma unroll
        for (int j = 0; j < 4; ++j)
          acc[i][j] += a[i].x * bv[j].x + a[i].y * bv[j].y + a[i].z * bv[j].z + a[i].w * bv[j].w;
    }

    // keys = |c|^2 - 2*dot  -> distb (b128 writes, conflict-free at stride 168)
    {
      float4 sqv = *(const float4*)(sqb + n0 + tx * 4);
      #pragma unroll
      for (int i = 0; i < 4; ++i) {
        int r = ty * 4 + i;
        float4 kv;
        kv.x = sqv.x - 2.f * acc[i][0];
        kv.y = sqv.y - 2.f * acc[i][1];
        kv.z = sqv.z - 2.f * acc[i][2];
        kv.w = sqv.w - 2.f * acc[i][3];
        *(float4*)(distb + r * 168 + tx * 4) = kv;
      }
    }
    __syncthreads();

    // selection: thread (selrow, selsub) scans its 16 cols, keeps sorted top-KSEL
    {
      const float* drow = distb + selrow * 168 + selsub * 16;
      int nbase = n0 + selsub * 16;
      #pragma unroll
      for (int q = 0; q < 16; q += 4) {
        float4 v = *(const float4*)(drow + q);
        float vv[4] = {v.x, v.y, v.z, v.w};
        #pragma unroll
        for (int e = 0; e < 4; ++e) {
          float key = vv[e]; int idx = nbase + q + e;
          if (key < kd[KSEL - 1]) {
            #pragma unroll
            for (int s = KSEL - 1; s > 0; --s) {
              bool sh = key < kd[s - 1];
              bool he = key < kd[s];
              kd[s] = sh ? kd[s - 1] : (he ? key : kd[s]);
              ki[s] = sh ? ki[s - 1] : (he ? idx : ki[s]);
            }
            if (key < kd[0]) { kd[0] = key; ki[0] = idx; }
          }
        }
      }
    }
  }

  __syncthreads();   // before reusing Ac/distb as merge buffers

  float* keybuf = Ac;             // [32][8][KSEL]
  int*   idxbuf = (int*)distb;    // [32][8][KSEL]
  {
    int base = (selrow * 8 + selsub) * KSEL;
    #pragma unroll
    for (int s = 0; s < KSEL; ++s) { keybuf[base + s] = kd[s]; idxbuf[base + s] = ki[s]; }
  }
  __syncthreads();

  // 8-way merge per row (one lane per row), lexicographic (key, idx) tie-break
  if (t < 32) {
    int row = t;
    int p[8] = {0, 0, 0, 0, 0, 0, 0, 0};
    for (int s = 0; s < KSEL; ++s) {
      float bk = INF; int bi = 0x7fffffff; int bj = -1;
      #pragma unroll
      for (int j = 0; j < 8; ++j) {
        int pj = p[j];
        bool ok = pj < KSEL;
        float k2 = ok ? keybuf[(row * 8 + j) * KSEL + pj] : INF;
        int   i2 = ok ? idxbuf[(row * 8 + j) * KSEL + pj] : 0x7fffffff;
        if (k2 < bk || (k2 == bk && i2 < bi)) { bk = k2; bi = i2; bj = j; }
      }
      cand[((size_t)b * N + row0 + row) * KSEL + s] = bi;
      #pragma unroll
      for (int j = 0; j < 8; ++j) p[j] += (bj == j) ? 1 : 0;
    }
  }
}

// ---------------- kernel 3: exact f64 re-rank of the 20 candidates ----------------
__global__ void refine_kernel(const float* __restrict__ pc, const int* __restrict__ cand,
                              int* __restrict__ knn) {
  int i = blockIdx.x * 256 + threadIdx.x;  // 0..16383
  int b = i >> 13, n = i & (N - 1);
  const float* pcb = pc + (size_t)b * D * N;
  int cid[KSEL]; double dd2[KSEL];
  #pragma unroll
  for (int j = 0; j < KSEL; ++j) { cid[j] = cand[(size_t)i * KSEL + j]; dd2[j] = 0.0; }
  for (int d = 0; d < D; ++d) {
    const float* rowp = pcb + (size_t)d * N;
    double qd = (double)rowp[n];
    #pragma unroll
    for (int j = 0; j < KSEL; ++j) {
      double diff = (double)rowp[cid[j]] - qd;
      dd2[j] = fma(diff, diff, dd2[j]);
    }
  }
  // unrolled bubble sort ascending by (dist, idx)
  #pragma unroll
  for (int a = 0; a < KSEL; ++a)
    #pragma unroll
    for (int c2 = 0; c2 < KSEL - 1 - a; ++c2) {
      bool sw = (dd2[c2] > dd2[c2 + 1]) ||
                (dd2[c2] == dd2[c2 + 1] && cid[c2] > cid[c2 + 1]);
      double t1 = sw ? dd2[c2 + 1] : dd2[c2];
      double t2 = sw ? dd2[c2] : dd2[c2 + 1];
      dd2[c2] = t1; dd2[c2 + 1] = t2;
      int u1 = sw ? cid[c2 + 1] : cid[c2];
      int u2 = sw ? cid[c2] : cid[c2 + 1];
      cid[c2] = u1; cid[c2 + 1] = u2;
    }
  #pragma unroll
  for (int k = 0; k < KOUT; ++k)
    knn[((size_t)b * KOUT + k) * N + n] = cid[k];
}

// ---------------- kernel 4: edge features ----------------
// out edge: [B][128][KOUT][N]; grid (N/256, KOUT, B*64)
__global__ void edge_kernel(const float* __restrict__ pc, const int* __restrict__ knn,
                            float* __restrict__ out) {
  int n = blockIdx.x * 256 + threadIdx.x;
  int k = blockIdx.y;
  int z = blockIdx.z;
  int b = z >> 6, c = z & 63;
  int nb = knn[((size_t)b * KOUT + k) * N + n];
  const float* row = pc + ((size_t)b * D + c) * N;
  float central = row[n];
  float nbrv = row[nb];
  size_t base = (((size_t)b * 2 * D + c) * KOUT + k) * N + n;
  out[base] = central;
  out[base + (size_t)D * KOUT * N] = nbrv - central;
}

// ---------------- kernel 5: idx as float ----------------
__global__ void idxout_kernel(const int* __restrict__ knn, float* __restrict__ out) {
  int i = blockIdx.x * 256 + threadIdx.x;   // 0..B*KOUT*N-1
  out[i] = (float)knn[i];
}

extern "C" void kernel_launch(void* const* d_in, const int* in_sizes, int n_in,
                              void* d_out, int out_size, void* d_ws, size_t ws_size,
                              hipStream_t stream) {
  const float* pc = (const float*)d_in[0];
  float* out = (float*)d_out;
  char* ws = (char*)d_ws;
  float* sq  = (float*)ws;                                    // 16384 f32 = 64 KB
  int*  cand = (int*)(ws + 65536);                            // 16384*20 int
  int*  knn  = (int*)(ws + 65536 + (size_t)16384 * KSEL * 4); // 2*17*8192 int

  sq_kernel<<<64, 256, 0, stream>>>(pc, sq);
  knn_select_kernel<<<512, 256, 0, stream>>>(pc, sq, cand);
  refine_kernel<<<64, 256, 0, stream>>>(pc, cand, knn);
  edge_kernel<<<dim3(N / 256, KOUT, B * 64), 256, 0, stream>>>(pc, knn, out);
  idxout_kernel<<<(B * KOUT * N) / 256, 256, 0, stream>>>(knn, out + (size_t)B * 2 * D * KOUT * N);
}

// Round 2
// 580.336 us; speedup vs baseline: 4.1413x; 4.1413x over previous
//
#include <hip/hip_runtime.h>

#define NPTS 8192
#define DIM 64
#define BATCH 2
#define KOUT 17
#define KSEL 20

typedef float f32x4 __attribute__((ext_vector_type(4)));
typedef short short8 __attribute__((ext_vector_type(8)));

// ---------- prep: hi/lo bf16 split (Phl[b][n][128]: 64 hi + 64 lo) + f64-accurate sq ----------
__global__ void prep_kernel(const float* __restrict__ pc, ushort* __restrict__ phl,
                            float* __restrict__ sq) {
  int i = blockIdx.x * 256 + threadIdx.x;  // 0..16383
  int b = i >> 13, n = i & (NPTS - 1);
  const float* g = pc + (size_t)b * DIM * NPTS + n;
  ushort* ph = phl + (size_t)i * 128;
  double s = 0.0;
  #pragma unroll
  for (int c = 0; c < 8; ++c) {
    short8 hv, lv;
    #pragma unroll
    for (int e = 0; e < 8; ++e) {
      int d = c * 8 + e;
      float x = g[(size_t)d * NPTS];
      s += (double)x * (double)x;
      unsigned u = __float_as_uint(x);
      unsigned r = u + (0x7fffu + ((u >> 16) & 1));
      unsigned hi = r >> 16;                       // bf16 RNE
      float xl = x - __uint_as_float(hi << 16);
      unsigned ul = __float_as_uint(xl);
      unsigned rl = ul + (0x7fffu + ((ul >> 16) & 1));
      hv[e] = (short)(hi & 0xffffu);
      lv[e] = (short)((rl >> 16) & 0xffffu);
    }
    *(short8*)(ph + c * 8) = hv;
    *(short8*)(ph + 64 + c * 8) = lv;
  }
  sq[i] = (float)s;
}

// ---------- fused MFMA distance + wave-coop top-20 ----------
// 512 blocks x 256 threads; block owns 32 rows of one batch; 64 col-tiles of 128.
__global__ __launch_bounds__(256, 2)
void knn_kernel(const ushort* __restrict__ phl, const float* __restrict__ sq,
                int* __restrict__ cand) {
  __shared__ ushort At[32 * 128];   // 8 KB  (per row: 64 hi | 64 lo, unit-swizzled)
  __shared__ ushort Bt[128 * 128];  // 32 KB
  __shared__ float  Sm[32 * 128];   // 16 KB (keys, col-swizzled)
  __shared__ float  sqs[128];

  int t = threadIdx.x;
  int lane = t & 63;
  int w = t >> 6;
  int bx = blockIdx.x;
  int b = bx >> 8;
  int row0 = (bx & 255) * 32;
  const ushort* pb = phl + (size_t)b * NPTS * 128;
  const float* sqb = sq + b * NPTS;

  // stage A tile (32 rows x 16 16B-units), swizzled: unit' = u7 ^ (n&7)
  #pragma unroll
  for (int it = 0; it < 2; ++it) {
    int unit = t + it * 256;            // 0..511
    int n = unit >> 4, u = unit & 15;
    short8 v = *(const short8*)(pb + (size_t)(row0 + n) * 128 + u * 8);
    int off = n * 128 + (u >> 3) * 64 + (((u & 7) * 8) ^ ((n & 7) << 3));
    *(short8*)(At + off) = v;
  }

  unsigned k8[8], i8[8];
  #pragma unroll
  for (int r = 0; r < 8; ++r) { k8[r] = 0xFFFFFFFFu; i8[r] = 0u; }

  int mrow = (w & 1) * 16;
  int ccol = (w >> 1) * 64;
  int l15 = lane & 15, l4 = lane >> 4;

  for (int tile = 0; tile < 64; ++tile) {
    int n0 = tile * 128;
    __syncthreads();
    // stage B tile (128 rows x 16 units)
    #pragma unroll
    for (int j = 0; j < 8; ++j) {
      int unit = t + j * 256;           // 0..2047
      int n = unit >> 4, u = unit & 15;
      short8 v = *(const short8*)(pb + (size_t)(n0 + n) * 128 + u * 8);
      int off = n * 128 + (u >> 3) * 64 + (((u & 7) * 8) ^ ((n & 7) << 3));
      *(short8*)(Bt + off) = v;
    }
    if (t < 128) sqs[t] = sqb[n0 + t];
    __syncthreads();

    // A fragments: [hl][kk], lane holds row mrow+l15, k = kk*32 + l4*8 + 0..7
    short8 a[2][2];
    #pragma unroll
    for (int hl = 0; hl < 2; ++hl)
      #pragma unroll
      for (int kk = 0; kk < 2; ++kk) {
        int n = mrow + l15;
        a[hl][kk] = *(const short8*)(At + n * 128 + hl * 64 +
                                     ((kk * 32 + l4 * 8) ^ ((n & 7) << 3)));
      }

    #pragma unroll
    for (int cf = 0; cf < 4; ++cf) {
      int col = ccol + cf * 16 + l15;   // tile-local col
      f32x4 acc = {0.f, 0.f, 0.f, 0.f};
      #pragma unroll
      for (int kk = 0; kk < 2; ++kk) {
        int bo = col * 128 + ((kk * 32 + l4 * 8) ^ ((col & 7) << 3));
        short8 bh = *(const short8*)(Bt + bo);
        short8 bl = *(const short8*)(Bt + bo + 64);
        acc = __builtin_amdgcn_mfma_f32_16x16x32_bf16(a[0][kk], bh, acc, 0, 0, 0);
        acc = __builtin_amdgcn_mfma_f32_16x16x32_bf16(a[0][kk], bl, acc, 0, 0, 0);
        acc = __builtin_amdgcn_mfma_f32_16x16x32_bf16(a[1][kk], bh, acc, 0, 0, 0);
      }
      float sqc = sqs[col];
      #pragma unroll
      for (int r = 0; r < 4; ++r) {
        int rowS = mrow + l4 * 4 + r;
        float key = fmaf(-2.f, acc[r], sqc);
        Sm[rowS * 128 + (col ^ ((rowS & 7) << 2))] = key;
      }
    }
    __syncthreads();

    // wave-cooperative selection: wave w owns rows w*8..w*8+7
    #pragma unroll
    for (int r = 0; r < 8; ++r) {
      int rowS = w * 8 + r;
      unsigned tau = __shfl(k8[r], 19);
      #pragma unroll
      for (int h = 0; h < 2; ++h) {
        int col = h * 64 + lane;
        float key = Sm[rowS * 128 + (col ^ ((rowS & 7) << 2))];
        unsigned u = __float_as_uint(key);
        unsigned keyu = u ^ (0x80000000u | (unsigned)(((int)u) >> 31));  // monotonic
        unsigned long long mask = __ballot(keyu < tau);
        while (mask) {
          int l = __builtin_ctzll(mask);
          mask &= mask - 1;
          unsigned ks = __shfl(keyu, l);
          if (ks < tau) {
            unsigned idxs = (unsigned)(n0 + h * 64 + l);
            unsigned pk = __shfl_up(k8[r], 1);
            unsigned pi = __shfl_up(i8[r], 1);
            if (lane == 0) pk = 0u;
            bool p1 = ks < pk;
            bool p2 = ks < k8[r];
            unsigned mx = ks > pk ? ks : pk;
            k8[r] = mx < k8[r] ? mx : k8[r];
            i8[r] = p1 ? pi : (p2 ? idxs : i8[r]);
            tau = __shfl(k8[r], 19);
          }
        }
      }
    }
  }

  if (lane < KSEL) {
    #pragma unroll
    for (int r = 0; r < 8; ++r) {
      int rowG = row0 + w * 8 + r;
      cand[((size_t)b * NPTS + rowG) * KSEL + lane] = (int)i8[r];
    }
  }
}

// ---------- exact f64 re-rank of the 20 candidates ----------
__global__ void refine_kernel(const float* __restrict__ pc, const int* __restrict__ cand,
                              int* __restrict__ knn) {
  int i = blockIdx.x * 256 + threadIdx.x;  // 0..16383
  int b = i >> 13, n = i & (NPTS - 1);
  const float* pcb = pc + (size_t)b * DIM * NPTS;
  int cid[KSEL]; double dd2[KSEL];
  #pragma unroll
  for (int j = 0; j < KSEL; ++j) { cid[j] = cand[(size_t)i * KSEL + j]; dd2[j] = 0.0; }
  for (int d = 0; d < DIM; ++d) {
    const float* rowp = pcb + (size_t)d * NPTS;
    double qd = (double)rowp[n];
    #pragma unroll
    for (int j = 0; j < KSEL; ++j) {
      double diff = (double)rowp[cid[j]] - qd;
      dd2[j] = fma(diff, diff, dd2[j]);
    }
  }
  #pragma unroll
  for (int a = 0; a < KSEL; ++a)
    #pragma unroll
    for (int c2 = 0; c2 < KSEL - 1 - a; ++c2) {
      bool sw = (dd2[c2] > dd2[c2 + 1]) ||
                (dd2[c2] == dd2[c2 + 1] && cid[c2] > cid[c2 + 1]);
      double t1 = sw ? dd2[c2 + 1] : dd2[c2];
      double t2 = sw ? dd2[c2] : dd2[c2 + 1];
      dd2[c2] = t1; dd2[c2 + 1] = t2;
      int u1 = sw ? cid[c2 + 1] : cid[c2];
      int u2 = sw ? cid[c2] : cid[c2 + 1];
      cid[c2] = u1; cid[c2 + 1] = u2;
    }
  #pragma unroll
  for (int k = 0; k < KOUT; ++k)
    knn[((size_t)b * KOUT + k) * NPTS + n] = cid[k];
}

// ---------- edge features: out [B][128][17][N] ----------
__global__ void edge_kernel(const float* __restrict__ pc, const int* __restrict__ knn,
                            float* __restrict__ out) {
  int n = blockIdx.x * 256 + threadIdx.x;
  int k = blockIdx.y;
  int z = blockIdx.z;
  int b = z >> 6, c = z & 63;
  int nb = knn[((size_t)b * KOUT + k) * NPTS + n];
  const float* row = pc + ((size_t)b * DIM + c) * NPTS;
  float central = row[n];
  float nbrv = row[nb];
  size_t base = (((size_t)b * 2 * DIM + c) * KOUT + k) * NPTS + n;
  out[base] = central;
  out[base + (size_t)DIM * KOUT * NPTS] = nbrv - central;
}

__global__ void idxout_kernel(const int* __restrict__ knn, float* __restrict__ out) {
  int i = blockIdx.x * 256 + threadIdx.x;
  out[i] = (float)knn[i];
}

extern "C" void kernel_launch(void* const* d_in, const int* in_sizes, int n_in,
                              void* d_out, int out_size, void* d_ws, size_t ws_size,
                              hipStream_t stream) {
  const float* pc = (const float*)d_in[0];
  float* out = (float*)d_out;
  char* ws = (char*)d_ws;
  ushort* phl = (ushort*)ws;                                   // 4 MB
  float* sq   = (float*)(ws + (size_t)16384 * 256);            // 64 KB
  int* cand   = (int*)(ws + (size_t)16384 * 256 + 65536);      // 1.28 MB
  int* knn    = (int*)(ws + (size_t)16384 * 256 + 65536 + (size_t)16384 * KSEL * 4);

  prep_kernel<<<64, 256, 0, stream>>>(pc, phl, sq);
  knn_kernel<<<512, 256, 0, stream>>>(phl, sq, cand);
  refine_kernel<<<64, 256, 0, stream>>>(pc, cand, knn);
  edge_kernel<<<dim3(NPTS / 256, KOUT, BATCH * DIM), 256, 0, stream>>>(pc, knn, out);
  idxout_kernel<<<(BATCH * KOUT * NPTS) / 256, 256, 0, stream>>>(
      knn, out + (size_t)BATCH * 2 * DIM * KOUT * NPTS);
}

// Round 3
// 410.141 us; speedup vs baseline: 5.8598x; 1.4150x over previous
//
#include <hip/hip_runtime.h>

#define NPTS 8192
#define DIM 64
#define BATCH 2
#define KOUT 17
#define KSEL 20   // per col-half

typedef float f32x4 __attribute__((ext_vector_type(4)));
typedef short short8 __attribute__((ext_vector_type(8)));

__device__ __forceinline__ void gload16(const void* g, void* lds) {
  __builtin_amdgcn_global_load_lds((const __attribute__((address_space(1))) void*)g,
                                   (__attribute__((address_space(3))) void*)lds, 16, 0, 0);
}

__device__ __forceinline__ unsigned mono(float x) {
  unsigned u = __float_as_uint(x);
  unsigned s = (unsigned)(((int)u) >> 31);
  return u ^ (0x80000000u | s);
}

// ---------- prep: permuted hi/lo bf16 (phl), transposed f32 (pct), f64 sq ----------
// phl[b*N+n][slot]: hi unit u at slot u^(n&7), lo unit u at slot 8+(u^(n&7)); unit u = dims 8u..8u+7
__global__ void prep_kernel(const float* __restrict__ pc, ushort* __restrict__ phl,
                            float* __restrict__ pct, float* __restrict__ sq) {
  int i = blockIdx.x * 256 + threadIdx.x;  // 0..16383
  int b = i >> 13, n = i & (NPTS - 1);
  const float* g = pc + (size_t)b * DIM * NPTS + n;
  ushort* ph = phl + (size_t)i * 128;
  float* pt = pct + (size_t)i * 64;
  double s = 0.0;
  int swz = n & 7;
  #pragma unroll
  for (int u = 0; u < 8; ++u) {
    float x[8];
    short8 hv, lv;
    #pragma unroll
    for (int e = 0; e < 8; ++e) {
      x[e] = g[(size_t)(u * 8 + e) * NPTS];
      s += (double)x[e] * (double)x[e];
      unsigned uu = __float_as_uint(x[e]);
      unsigned r = uu + (0x7fffu + ((uu >> 16) & 1));
      unsigned hi = r >> 16;
      float xl = x[e] - __uint_as_float(hi << 16);
      unsigned ul = __float_as_uint(xl);
      unsigned rl = ul + (0x7fffu + ((ul >> 16) & 1));
      hv[e] = (short)(hi & 0xffffu);
      lv[e] = (short)((rl >> 16) & 0xffffu);
    }
    int slot = u ^ swz;
    *(short8*)(ph + slot * 8) = hv;
    *(short8*)(ph + 64 + slot * 8) = lv;
    f32x4 v0 = {x[0], x[1], x[2], x[3]}, v1 = {x[4], x[5], x[6], x[7]};
    *(f32x4*)(pt + u * 8) = v0;
    *(f32x4*)(pt + u * 8 + 4) = v1;
  }
  sq[i] = (float)s;
}

// ---------- fused MFMA distance + quarter-wave register top-20 ----------
// 512 blocks x 256 threads; block = 32 rows; 64 col-tiles of 128; wave = 16 rows x 64 cols.
__global__ __launch_bounds__(256, 4)
void knn_kernel(const ushort* __restrict__ phl, const float* __restrict__ sq,
                int* __restrict__ cand) {
  __shared__ ushort Bt[128 * 128];  // 32 KB, linear [point][slot] (pre-permuted)

  int t = threadIdx.x;
  int lane = t & 63;
  int w = t >> 6;
  int b = blockIdx.x >> 8;
  int row0 = (blockIdx.x & 255) * 32;
  const ushort* pb = phl + (size_t)b * NPTS * 128;
  const float* sqb = sq + b * NPTS;

  int l15 = lane & 15, l4 = lane >> 4;
  int mrow = (w & 1) * 16;
  int ccol = (w >> 1) * 64;
  int hh = w >> 1;

  // A fragments from global (pre-permuted layout), once
  short8 a[2][2];
  {
    int n = row0 + mrow + l15;
    const ushort* pr = pb + (size_t)n * 128;
    #pragma unroll
    for (int kk = 0; kk < 2; ++kk) {
      int slot = (kk * 4 + l4) ^ (n & 7);
      a[0][kk] = *(const short8*)(pr + slot * 8);
      a[1][kk] = *(const short8*)(pr + 64 + slot * 8);
    }
  }

  // distributed sorted top-20 per (quarter q=l4, r): slots = lane_local*2+{0,1}, lanes 0..9
  unsigned v0[4], v1[4], id0[4], id1[4], tau[4];
  #pragma unroll
  for (int r = 0; r < 4; ++r) {
    v0[r] = 0xFFFFFFFFu; v1[r] = 0xFFFFFFFFu;
    id0[r] = 0u; id1[r] = 0u; tau[r] = 0xFFFFFFFFu;
  }

  for (int tile = 0; tile < 64; ++tile) {
    int n0 = tile * 128;
    __syncthreads();
    // DMA stage: wave w stages points n0+w*32 .. +31 (8 KB), linear
    #pragma unroll
    for (int j = 0; j < 8; ++j) {
      const ushort* src = pb + (size_t)(n0 + w * 32 + j * 4 + (lane >> 4)) * 128 + (lane & 15) * 8;
      gload16(src, Bt + (w * 32 + j * 4) * 128);
    }
    // prefetch sq for this tile's cols
    float sqv[4];
    #pragma unroll
    for (int cf = 0; cf < 4; ++cf) sqv[cf] = sqb[n0 + ccol + cf * 16 + l15];
    __syncthreads();

    // MFMA: acc[cf] covers rows mrow+l4*4+r, col ccol+cf*16+l15
    f32x4 acc[4];
    #pragma unroll
    for (int cf = 0; cf < 4; ++cf) {
      int lc = ccol + cf * 16 + l15;
      const ushort* bp = Bt + lc * 128;
      f32x4 c = {0.f, 0.f, 0.f, 0.f};
      #pragma unroll
      for (int kk = 0; kk < 2; ++kk) {
        int so = ((kk * 4 + l4) ^ (lc & 7)) * 8;
        short8 bh = *(const short8*)(bp + so);
        short8 bl = *(const short8*)(bp + 64 + so);
        c = __builtin_amdgcn_mfma_f32_16x16x32_bf16(a[0][kk], bh, c, 0, 0, 0);
        c = __builtin_amdgcn_mfma_f32_16x16x32_bf16(a[0][kk], bl, c, 0, 0, 0);
        c = __builtin_amdgcn_mfma_f32_16x16x32_bf16(a[1][kk], bh, c, 0, 0, 0);
      }
      acc[cf] = c;
    }

    // quarter-wave selection: quarter q=l4 owns rows mrow+q*4+r
    int n0c = n0 + ccol;
    #pragma unroll
    for (int r = 0; r < 4; ++r) {
      #pragma unroll
      for (int cf = 0; cf < 4; ++cf) {
        unsigned keyu = mono(fmaf(-2.f, acc[cf][r], sqv[cf]));
        unsigned long long m = __ballot(keyu < tau[r]);
        unsigned qmask = (unsigned)((m >> (l4 * 16)) & 0xFFFFull);
        while (qmask) {
          int l = __builtin_ctz(qmask);
          qmask &= qmask - 1;
          unsigned ks = __shfl(keyu, l4 * 16 + l);
          if (ks < tau[r]) {
            unsigned nid = (unsigned)(n0c + cf * 16 + l);
            unsigned p = __shfl_up(v1[r], 1, 16);
            unsigned pid = __shfl_up(id1[r], 1, 16);
            if (l15 == 0) p = 0u;
            unsigned ov0 = v0[r], oid0 = id0[r];
            bool geV0 = ks >= ov0;
            bool geP = ks >= p;
            unsigned t0 = ks > p ? ks : p;
            v0[r] = t0 < ov0 ? t0 : ov0;
            id0[r] = geV0 ? oid0 : (geP ? nid : pid);
            unsigned t1 = ks > ov0 ? ks : ov0;
            unsigned ov1 = v1[r];
            v1[r] = t1 < ov1 ? t1 : ov1;
            id1[r] = (ks >= ov1) ? id1[r] : (geV0 ? nid : oid0);
            tau[r] = __shfl(v1[r], (lane & 48) | 9);
          }
        }
      }
    }
  }

  // output: 20 candidates per (row, col-half)
  #pragma unroll
  for (int r = 0; r < 4; ++r) {
    if (l15 < 10) {
      int row = row0 + mrow + l4 * 4 + r;
      size_t base = ((size_t)(b * NPTS + row) * 2 + hh) * KSEL + l15 * 2;
      cand[base] = (int)id0[r];
      cand[base + 1] = (int)id1[r];
    }
  }
}

// ---------- exact f64 re-rank of 40 candidates, wave per point ----------
__global__ void refine_kernel(const float* __restrict__ pct, const int* __restrict__ cand,
                              int* __restrict__ knn, float* __restrict__ idxf) {
  int gw = (blockIdx.x * 256 + threadIdx.x) >> 6;  // 0..16383
  int lane = threadIdx.x & 63;
  int b = gw >> 13, n = gw & (NPTS - 1);
  const float* pcb = pct + (size_t)b * NPTS * 64;
  int cid = 0x7fffffff;
  double d2 = __builtin_inf();
  if (lane < 2 * KSEL) {
    cid = cand[(size_t)gw * (2 * KSEL) + lane];
    const float* cp = pcb + (size_t)cid * 64;
    const float* qp = pcb + (size_t)n * 64;
    double s = 0.0;
    #pragma unroll
    for (int u = 0; u < 16; ++u) {
      f32x4 cv = *(const f32x4*)(cp + u * 4);
      f32x4 qv = *(const f32x4*)(qp + u * 4);
      #pragma unroll
      for (int e = 0; e < 4; ++e) {
        double diff = (double)cv[e] - (double)qv[e];
        s = fma(diff, diff, s);
      }
    }
    d2 = s;
  }
  int rank = 0;
  #pragma unroll
  for (int l = 0; l < 2 * KSEL; ++l) {
    double dk = __shfl(d2, l);
    int ik = __shfl(cid, l);
    rank += ((dk < d2) || (dk == d2 && ik < cid)) ? 1 : 0;
  }
  if (lane < 2 * KSEL && rank < KOUT) {
    size_t o = ((size_t)b * KOUT + rank) * NPTS + n;
    knn[o] = cid;
    idxf[o] = (float)cid;
  }
}

// ---------- edge features: out [B][128][17][N] ----------
__global__ void edge_kernel(const float* __restrict__ pc, const int* __restrict__ knn,
                            float* __restrict__ out) {
  int n = blockIdx.x * 256 + threadIdx.x;
  int k = blockIdx.y;
  int z = blockIdx.z;
  int b = z >> 6, c = z & 63;
  int nb = knn[((size_t)b * KOUT + k) * NPTS + n];
  const float* row = pc + ((size_t)b * DIM + c) * NPTS;
  float central = row[n];
  float nbrv = row[nb];
  size_t base = (((size_t)b * 2 * DIM + c) * KOUT + k) * NPTS + n;
  out[base] = central;
  out[base + (size_t)DIM * KOUT * NPTS] = nbrv - central;
}

extern "C" void kernel_launch(void* const* d_in, const int* in_sizes, int n_in,
                              void* d_out, int out_size, void* d_ws, size_t ws_size,
                              hipStream_t stream) {
  const float* pc = (const float*)d_in[0];
  float* out = (float*)d_out;
  char* ws = (char*)d_ws;
  ushort* phl = (ushort*)ws;                                   // 4 MB
  float* pct  = (float*)(ws + (size_t)4 * 1024 * 1024);        // 4 MB
  float* sq   = (float*)(ws + (size_t)8 * 1024 * 1024);        // 64 KB
  int* cand   = (int*)(ws + (size_t)8 * 1024 * 1024 + 65536);  // 2.56 MB
  int* knn    = (int*)(ws + (size_t)8 * 1024 * 1024 + 65536 + (size_t)16384 * 2 * KSEL * 4);

  float* idxf = out + (size_t)BATCH * 2 * DIM * KOUT * NPTS;

  prep_kernel<<<64, 256, 0, stream>>>(pc, phl, pct, sq);
  knn_kernel<<<512, 256, 0, stream>>>(phl, sq, cand);
  refine_kernel<<<4096, 256, 0, stream>>>(pct, cand, knn, idxf);
  edge_kernel<<<dim3(NPTS / 256, KOUT, BATCH * DIM), 256, 0, stream>>>(pc, knn, out);
}

// Round 4
// 332.344 us; speedup vs baseline: 7.2315x; 1.2341x over previous
//
#include <hip/hip_runtime.h>

#define NPTS 8192
#define DIM 64
#define BATCH 2
#define KOUT 17
#define KSEL 20   // per (row, col-segment)

typedef float f32x4 __attribute__((ext_vector_type(4)));
typedef short short8 __attribute__((ext_vector_type(8)));

__device__ __forceinline__ void gload16(const void* g, void* lds) {
  __builtin_amdgcn_global_load_lds((const __attribute__((address_space(1))) void*)g,
                                   (__attribute__((address_space(3))) void*)lds, 16, 0, 0);
}

__device__ __forceinline__ unsigned mono(float x) {
  unsigned u = __float_as_uint(x);
  unsigned s = (unsigned)(((int)u) >> 31);
  return u ^ (0x80000000u | s);
}

// ---------- prep: permuted hi/lo bf16 (phl), transposed f32 (pct), f64 sq ----------
// thread = (unit u = t>>5 .. wait: u = t/32? we use u = t>>5? No: 8 units x 32 points)
__global__ __launch_bounds__(256)
void prep_kernel(const float* __restrict__ pc, ushort* __restrict__ phl,
                 float* __restrict__ pct, float* __restrict__ sq) {
  __shared__ double psum[256];
  int t = threadIdx.x;
  int u = t >> 5;           // 0..7  (dims u*8 .. u*8+7)
  int p = t & 31;           // 0..31 (point within block)
  int i = blockIdx.x * 32 + p;   // 0..16383
  int b = i >> 13, n = i & (NPTS - 1);
  const float* g = pc + (size_t)b * DIM * NPTS + n;

  float x[8];
  short8 hv, lv;
  double s = 0.0;
  #pragma unroll
  for (int e = 0; e < 8; ++e) {
    x[e] = g[(size_t)(u * 8 + e) * NPTS];
    s += (double)x[e] * (double)x[e];
    unsigned uu = __float_as_uint(x[e]);
    unsigned r = uu + (0x7fffu + ((uu >> 16) & 1));
    unsigned hi = r >> 16;                       // bf16 RNE
    float xl = x[e] - __uint_as_float(hi << 16);
    unsigned ul = __float_as_uint(xl);
    unsigned rl = ul + (0x7fffu + ((ul >> 16) & 1));
    hv[e] = (short)(hi & 0xffffu);
    lv[e] = (short)((rl >> 16) & 0xffffu);
  }
  int slot = u ^ (n & 7);
  ushort* ph = phl + (size_t)i * 128;
  *(short8*)(ph + slot * 8) = hv;
  *(short8*)(ph + 64 + slot * 8) = lv;
  f32x4 v0 = {x[0], x[1], x[2], x[3]}, v1 = {x[4], x[5], x[6], x[7]};
  *(f32x4*)(pct + (size_t)i * 64 + u * 8) = v0;
  *(f32x4*)(pct + (size_t)i * 64 + u * 8 + 4) = v1;

  psum[u * 32 + p] = s;
  __syncthreads();
  if (t < 32) {
    double acc = 0.0;
    #pragma unroll
    for (int uu = 0; uu < 8; ++uu) acc += psum[uu * 32 + t];
    sq[blockIdx.x * 32 + t] = (float)acc;
  }
}

// ---------- fused MFMA distance + quarter-wave register top-20 ----------
// 1024 blocks x 256 threads; block = 32 rows x 4096 cols (32 tiles of 128).
__global__ __launch_bounds__(256, 4)
void knn_kernel(const ushort* __restrict__ phl, const float* __restrict__ sq,
                int* __restrict__ cand) {
  __shared__ ushort Bt[128 * 128];  // 32 KB, linear [point][slot] (pre-permuted)

  int t = threadIdx.x;
  int lane = t & 63;
  int w = t >> 6;
  int b = blockIdx.x >> 9;
  int seg = (blockIdx.x >> 8) & 1;
  int row0 = (blockIdx.x & 255) * 32;
  const ushort* pb = phl + (size_t)b * NPTS * 128;
  const float* sqb = sq + b * NPTS;

  int l15 = lane & 15, l4 = lane >> 4;
  int mrow = (w & 1) * 16;
  int ccol = (w >> 1) * 64;
  int hh = w >> 1;

  // A fragments from global (pre-permuted layout), once
  short8 a[2][2];
  {
    int n = row0 + mrow + l15;
    const ushort* pr = pb + (size_t)n * 128;
    #pragma unroll
    for (int kk = 0; kk < 2; ++kk) {
      int slot = (kk * 4 + l4) ^ (n & 7);
      a[0][kk] = *(const short8*)(pr + slot * 8);
      a[1][kk] = *(const short8*)(pr + 64 + slot * 8);
    }
  }

  // distributed sorted top-20 per (quarter q=l4, r): 2 slots/lane in lanes 0..9
  unsigned v0[4], v1[4], id0[4], id1[4], tau[4];
  #pragma unroll
  for (int r = 0; r < 4; ++r) {
    v0[r] = 0xFFFFFFFFu; v1[r] = 0xFFFFFFFFu;
    id0[r] = 0u; id1[r] = 0u; tau[r] = 0xFFFFFFFFu;
  }

  for (int tile = 0; tile < 32; ++tile) {
    int n0 = (seg * 32 + tile) * 128;
    __syncthreads();
    // DMA stage: wave w stages points n0+w*32 .. +31 (8 KB), linear
    #pragma unroll
    for (int j = 0; j < 8; ++j) {
      const ushort* src = pb + (size_t)(n0 + w * 32 + j * 4 + (lane >> 4)) * 128 + (lane & 15) * 8;
      gload16(src, Bt + (w * 32 + j * 4) * 128);
    }
    float sqv[4];
    #pragma unroll
    for (int cf = 0; cf < 4; ++cf) sqv[cf] = sqb[n0 + ccol + cf * 16 + l15];
    __syncthreads();

    // MFMA: acc[cf] covers rows mrow+l4*4+r, col ccol+cf*16+l15
    f32x4 acc[4];
    #pragma unroll
    for (int cf = 0; cf < 4; ++cf) {
      int lc = ccol + cf * 16 + l15;
      const ushort* bp = Bt + lc * 128;
      f32x4 c = {0.f, 0.f, 0.f, 0.f};
      #pragma unroll
      for (int kk = 0; kk < 2; ++kk) {
        int so = ((kk * 4 + l4) ^ (lc & 7)) * 8;
        short8 bh = *(const short8*)(bp + so);
        short8 bl = *(const short8*)(bp + 64 + so);
        c = __builtin_amdgcn_mfma_f32_16x16x32_bf16(a[0][kk], bh, c, 0, 0, 0);
        c = __builtin_amdgcn_mfma_f32_16x16x32_bf16(a[0][kk], bl, c, 0, 0, 0);
        c = __builtin_amdgcn_mfma_f32_16x16x32_bf16(a[1][kk], bh, c, 0, 0, 0);
      }
      acc[cf] = c;
    }

    // quarter-wave selection: quarter q=l4 owns rows mrow+q*4+r
    int n0c = n0 + ccol;
    #pragma unroll
    for (int r = 0; r < 4; ++r) {
      #pragma unroll
      for (int cf = 0; cf < 4; ++cf) {
        unsigned keyu = mono(fmaf(-2.f, acc[cf][r], sqv[cf]));
        unsigned long long m = __ballot(keyu < tau[r]);
        unsigned qmask = (unsigned)((m >> (l4 * 16)) & 0xFFFFull);
        if (qmask) {
          do {
            int l = __builtin_ctz(qmask);
            qmask &= qmask - 1;
            unsigned ks = __shfl(keyu, l4 * 16 + l);
            unsigned nid = (unsigned)(n0c + cf * 16 + l);
            unsigned p = __shfl_up(v1[r], 1, 16);
            unsigned pid = __shfl_up(id1[r], 1, 16);
            if (l15 == 0) p = 0u;
            unsigned ov0 = v0[r], oid0 = id0[r];
            bool geV0 = ks >= ov0;
            bool geP = ks >= p;
            unsigned t0 = ks > p ? ks : p;
            v0[r] = t0 < ov0 ? t0 : ov0;
            id0[r] = geV0 ? oid0 : (geP ? nid : pid);
            unsigned t1 = ks > ov0 ? ks : ov0;
            unsigned ov1 = v1[r];
            v1[r] = t1 < ov1 ? t1 : ov1;
            id1[r] = (ks >= ov1) ? id1[r] : (geV0 ? nid : oid0);
          } while (qmask);
          tau[r] = __shfl(v1[r], (lane & 48) | 9);
        }
      }
    }
  }

  // ---- in-block merge of the two col-half lists -> top-20 of this segment ----
  __syncthreads();
  unsigned* Km = (unsigned*)Bt;          // [32][2][20]
  unsigned* Im = Km + 32 * 40;           // [32][2][20]
  #pragma unroll
  for (int r = 0; r < 4; ++r) {
    if (l15 < 10) {
      int row = mrow + l4 * 4 + r;
      int base = row * 40 + hh * 20 + l15 * 2;
      Km[base] = v0[r]; Km[base + 1] = v1[r];
      Im[base] = id0[r]; Im[base + 1] = id1[r];
    }
  }
  __syncthreads();
  // wave w merges rows w*8 .. w*8+7 via rank-merge
  for (int rr = 0; rr < 8; ++rr) {
    int row = w * 8 + rr;
    if (lane < 40) {
      int h = lane >= 20 ? 1 : 0;
      int pos = lane - h * 20;
      unsigned key = Km[row * 40 + lane];
      unsigned idv = Im[row * 40 + lane];
      const unsigned* other = Km + row * 40 + (h ? 0 : 20);
      int rank = pos;
      #pragma unroll
      for (int j = 0; j < 20; ++j) {
        unsigned ok = other[j];
        rank += (ok < key || (ok == key && h == 1)) ? 1 : 0;
      }
      if (rank < KSEL)
        cand[((size_t)(b * NPTS + row0 + row) * 2 + seg) * KSEL + rank] = (int)idv;
    }
  }
}

// ---------- exact f64 re-rank of 40 candidates, wave per point ----------
__global__ void refine_kernel(const float* __restrict__ pct, const int* __restrict__ cand,
                              int* __restrict__ knn, float* __restrict__ idxf) {
  int gw = (blockIdx.x * 256 + threadIdx.x) >> 6;  // 0..16383
  int lane = threadIdx.x & 63;
  int b = gw >> 13, n = gw & (NPTS - 1);
  const float* pcb = pct + (size_t)b * NPTS * 64;
  int cid = 0x7fffffff;
  double d2 = __builtin_inf();
  if (lane < 2 * KSEL) {
    cid = cand[(size_t)gw * (2 * KSEL) + lane];
    const float* cp = pcb + (size_t)cid * 64;
    const float* qp = pcb + (size_t)n * 64;
    double s = 0.0;
    #pragma unroll
    for (int u = 0; u < 16; ++u) {
      f32x4 cv = *(const f32x4*)(cp + u * 4);
      f32x4 qv = *(const f32x4*)(qp + u * 4);
      #pragma unroll
      for (int e = 0; e < 4; ++e) {
        double diff = (double)cv[e] - (double)qv[e];
        s = fma(diff, diff, s);
      }
    }
    d2 = s;
  }
  int rank = 0;
  #pragma unroll
  for (int l = 0; l < 2 * KSEL; ++l) {
    double dk = __shfl(d2, l);
    int ik = __shfl(cid, l);
    rank += ((dk < d2) || (dk == d2 && ik < cid)) ? 1 : 0;
  }
  if (lane < 2 * KSEL && rank < KOUT) {
    size_t o = ((size_t)b * KOUT + rank) * NPTS + n;
    knn[o] = cid;
    idxf[o] = (float)cid;
  }
}

// ---------- edge features: out [B][128][17][N] ----------
__global__ void edge_kernel(const float* __restrict__ pc, const int* __restrict__ knn,
                            float* __restrict__ out) {
  int n = blockIdx.x * 256 + threadIdx.x;
  int k = blockIdx.y;
  int z = blockIdx.z;
  int b = z >> 6, c = z & 63;
  int nb = knn[((size_t)b * KOUT + k) * NPTS + n];
  const float* row = pc + ((size_t)b * DIM + c) * NPTS;
  float central = row[n];
  float nbrv = row[nb];
  size_t base = (((size_t)b * 2 * DIM + c) * KOUT + k) * NPTS + n;
  out[base] = central;
  out[base + (size_t)DIM * KOUT * NPTS] = nbrv - central;
}

extern "C" void kernel_launch(void* const* d_in, const int* in_sizes, int n_in,
                              void* d_out, int out_size, void* d_ws, size_t ws_size,
                              hipStream_t stream) {
  const float* pc = (const float*)d_in[0];
  float* out = (float*)d_out;
  char* ws = (char*)d_ws;
  ushort* phl = (ushort*)ws;                                   // 4 MB
  float* pct  = (float*)(ws + (size_t)4 * 1024 * 1024);        // 4 MB
  float* sq   = (float*)(ws + (size_t)8 * 1024 * 1024);        // 64 KB
  int* cand   = (int*)(ws + (size_t)8 * 1024 * 1024 + 65536);  // 2.56 MB
  int* knn    = (int*)(ws + (size_t)8 * 1024 * 1024 + 65536 + (size_t)16384 * 2 * KSEL * 4);

  float* idxf = out + (size_t)BATCH * 2 * DIM * KOUT * NPTS;

  prep_kernel<<<512, 256, 0, stream>>>(pc, phl, pct, sq);
  knn_kernel<<<1024, 256, 0, stream>>>(phl, sq, cand);
  refine_kernel<<<4096, 256, 0, stream>>>(pct, cand, knn, idxf);
  edge_kernel<<<dim3(NPTS / 256, KOUT, BATCH * DIM), 256, 0, stream>>>(pc, knn, out);
}

// Round 5
// 255.157 us; speedup vs baseline: 9.4192x; 1.3025x over previous
//
#include <hip/hip_runtime.h>

#define NPTS 8192
#define DIM 64
#define BATCH 2
#define KOUT 17
#define QCAP 40      // queue capacity per (row, seg)
#define THRANK 21    // theta = 22nd smallest of the 64-subset

typedef float f32x4 __attribute__((ext_vector_type(4)));
typedef short short8 __attribute__((ext_vector_type(8)));

__device__ __forceinline__ void gload16(const void* g, void* lds) {
  __builtin_amdgcn_global_load_lds((const __attribute__((address_space(1))) void*)g,
                                   (__attribute__((address_space(3))) void*)lds, 16, 0, 0);
}

__device__ __forceinline__ unsigned mono(float x) {
  unsigned u = __float_as_uint(x);
  unsigned s = (unsigned)(((int)u) >> 31);
  return u ^ (0x80000000u | s);
}

// ---------- prep: permuted hi/lo bf16 (phl), contiguous f32 (pct), f64 sq ----------
__global__ __launch_bounds__(256)
void prep_kernel(const float* __restrict__ pc, ushort* __restrict__ phl,
                 float* __restrict__ pct, float* __restrict__ sq) {
  __shared__ double psum[256];
  int t = threadIdx.x;
  int u = t >> 5;           // 0..7  (dims u*8 .. u*8+7)
  int p = t & 31;           // 0..31 (point within block)
  int i = blockIdx.x * 32 + p;   // 0..16383
  int b = i >> 13, n = i & (NPTS - 1);
  const float* g = pc + (size_t)b * DIM * NPTS + n;

  float x[8];
  short8 hv, lv;
  double s = 0.0;
  #pragma unroll
  for (int e = 0; e < 8; ++e) {
    x[e] = g[(size_t)(u * 8 + e) * NPTS];
    s += (double)x[e] * (double)x[e];
    unsigned uu = __float_as_uint(x[e]);
    unsigned r = uu + (0x7fffu + ((uu >> 16) & 1));
    unsigned hi = r >> 16;                       // bf16 RNE
    float xl = x[e] - __uint_as_float(hi << 16);
    unsigned ul = __float_as_uint(xl);
    unsigned rl = ul + (0x7fffu + ((ul >> 16) & 1));
    hv[e] = (short)(hi & 0xffffu);
    lv[e] = (short)((rl >> 16) & 0xffffu);
  }
  int slot = u ^ (n & 7);
  ushort* ph = phl + (size_t)i * 128;
  *(short8*)(ph + slot * 8) = hv;
  *(short8*)(ph + 64 + slot * 8) = lv;
  f32x4 v0 = {x[0], x[1], x[2], x[3]}, v1 = {x[4], x[5], x[6], x[7]};
  *(f32x4*)(pct + (size_t)i * 64 + u * 8) = v0;
  *(f32x4*)(pct + (size_t)i * 64 + u * 8 + 4) = v1;

  psum[u * 32 + p] = s;
  __syncthreads();
  if (t < 32) {
    double acc = 0.0;
    #pragma unroll
    for (int uu = 0; uu < 8; ++uu) acc += psum[uu * 32 + t];
    sq[blockIdx.x * 32 + t] = (float)acc;
  }
}

// ---------- two-pass MFMA distance + theta-filter collect ----------
// 1024 blocks x 256 threads; block = 32 rows x 2048 cols (seg), 16 tiles... (32 tiles of 128? seg=2048? no: 4096)
// block = (b, seg, rowgroup): 32 rows x 4096 cols = 32 tiles of 128.
__global__ __launch_bounds__(256, 4)
void knn_kernel(const ushort* __restrict__ phl, const float* __restrict__ sq,
                ushort* __restrict__ cand) {
  __shared__ ushort Bt[128 * 128];  // 32 KB; aliased as KT[32][64] between passes
  __shared__ unsigned TH[32];
  __shared__ int CNT[32];
  __shared__ ushort QU[32][QCAP];

  int t = threadIdx.x;
  int lane = t & 63;
  int w = t >> 6;
  int b = blockIdx.x >> 9;
  int seg = (blockIdx.x >> 8) & 1;
  int row0 = (blockIdx.x & 255) * 32;
  const ushort* pb = phl + (size_t)b * NPTS * 128;
  const float* sqb = sq + b * NPTS;

  int c15 = lane & 15, l4 = lane >> 4;
  int mrow = (w & 1) * 16;
  int ccol = (w >> 1) * 64;
  int hh = w >> 1;

  // A fragments from global (pre-permuted layout), once
  short8 a[2][2];
  {
    int n = row0 + mrow + c15;
    const ushort* pr = pb + (size_t)n * 128;
    #pragma unroll
    for (int kk = 0; kk < 2; ++kk) {
      int slot = (kk * 4 + l4) ^ (n & 7);
      a[0][kk] = *(const short8*)(pr + slot * 8);
      a[1][kk] = *(const short8*)(pr + 64 + slot * 8);
    }
  }

  // ================= PASS A: per-lane top-2 keys per owned row =================
  unsigned k1[4], k2[4];
  #pragma unroll
  for (int r = 0; r < 4; ++r) { k1[r] = 0xFFFFFFFFu; k2[r] = 0xFFFFFFFFu; }

  for (int tile = 0; tile < 32; ++tile) {
    int n0 = (seg * 32 + tile) * 128;
    __syncthreads();
    #pragma unroll
    for (int j = 0; j < 8; ++j) {
      const ushort* src = pb + (size_t)(n0 + w * 32 + j * 4 + (lane >> 4)) * 128 + (lane & 15) * 8;
      gload16(src, Bt + (w * 32 + j * 4) * 128);
    }
    float sqv[4];
    #pragma unroll
    for (int cf = 0; cf < 4; ++cf) sqv[cf] = sqb[n0 + ccol + cf * 16 + c15];
    __syncthreads();

    #pragma unroll
    for (int cf = 0; cf < 4; ++cf) {
      int lc = ccol + cf * 16 + c15;
      const ushort* bp = Bt + lc * 128;
      f32x4 c = {0.f, 0.f, 0.f, 0.f};
      #pragma unroll
      for (int kk = 0; kk < 2; ++kk) {
        int so = ((kk * 4 + l4) ^ (lc & 7)) * 8;
        short8 bh = *(const short8*)(bp + so);
        short8 bl = *(const short8*)(bp + 64 + so);
        c = __builtin_amdgcn_mfma_f32_16x16x32_bf16(a[0][kk], bh, c, 0, 0, 0);
        c = __builtin_amdgcn_mfma_f32_16x16x32_bf16(a[0][kk], bl, c, 0, 0, 0);
        c = __builtin_amdgcn_mfma_f32_16x16x32_bf16(a[1][kk], bh, c, 0, 0, 0);
      }
      #pragma unroll
      for (int r = 0; r < 4; ++r) {
        unsigned keyu = mono(fmaf(-2.f, c[r], sqv[cf]));
        unsigned mx = keyu > k1[r] ? keyu : k1[r];
        k2[r] = mx < k2[r] ? mx : k2[r];
        k1[r] = keyu < k1[r] ? keyu : k1[r];
      }
    }
  }

  // ================= theta per row = 22nd smallest of 64-subset =================
  __syncthreads();
  unsigned* KT = (unsigned*)Bt;   // [32][64]
  #pragma unroll
  for (int r = 0; r < 4; ++r) {
    int row = mrow + l4 * 4 + r;
    KT[row * 64 + hh * 32 + c15 * 2] = k1[r];
    KT[row * 64 + hh * 32 + c15 * 2 + 1] = k2[r];
  }
  __syncthreads();
  {
    int row = t >> 3;
    int j0 = (t & 7) * 8;
    const uint4* vr4 = (const uint4*)(KT + row * 64);
    unsigned vj[8];
    *(uint4*)vj = vr4[(t & 7) * 2];
    *(uint4*)(vj + 4) = vr4[(t & 7) * 2 + 1];
    int rank[8];
    #pragma unroll
    for (int jj = 0; jj < 8; ++jj) rank[jj] = 0;
    for (int m4 = 0; m4 < 16; ++m4) {
      uint4 vm = vr4[m4];
      unsigned ve[4] = {vm.x, vm.y, vm.z, vm.w};
      #pragma unroll
      for (int e = 0; e < 4; ++e) {
        int m = m4 * 4 + e;
        #pragma unroll
        for (int jj = 0; jj < 8; ++jj)
          rank[jj] += (ve[e] < vj[jj] || (ve[e] == vj[jj] && m < j0 + jj)) ? 1 : 0;
      }
    }
    #pragma unroll
    for (int jj = 0; jj < 8; ++jj)
      if (rank[jj] == THRANK) TH[row] = vj[jj];
    if (t < 32) CNT[t] = 0;
  }
  __syncthreads();
  unsigned th[4];
  #pragma unroll
  for (int r = 0; r < 4; ++r) th[r] = TH[mrow + l4 * 4 + r];

  // ================= PASS B: recompute + collect key<=theta =================
  for (int tile = 0; tile < 32; ++tile) {
    int n0 = (seg * 32 + tile) * 128;
    __syncthreads();
    #pragma unroll
    for (int j = 0; j < 8; ++j) {
      const ushort* src = pb + (size_t)(n0 + w * 32 + j * 4 + (lane >> 4)) * 128 + (lane & 15) * 8;
      gload16(src, Bt + (w * 32 + j * 4) * 128);
    }
    float sqv[4];
    #pragma unroll
    for (int cf = 0; cf < 4; ++cf) sqv[cf] = sqb[n0 + ccol + cf * 16 + c15];
    __syncthreads();

    #pragma unroll
    for (int cf = 0; cf < 4; ++cf) {
      int lc = ccol + cf * 16 + c15;
      const ushort* bp = Bt + lc * 128;
      f32x4 c = {0.f, 0.f, 0.f, 0.f};
      #pragma unroll
      for (int kk = 0; kk < 2; ++kk) {
        int so = ((kk * 4 + l4) ^ (lc & 7)) * 8;
        short8 bh = *(const short8*)(bp + so);
        short8 bl = *(const short8*)(bp + 64 + so);
        c = __builtin_amdgcn_mfma_f32_16x16x32_bf16(a[0][kk], bh, c, 0, 0, 0);
        c = __builtin_amdgcn_mfma_f32_16x16x32_bf16(a[0][kk], bl, c, 0, 0, 0);
        c = __builtin_amdgcn_mfma_f32_16x16x32_bf16(a[1][kk], bh, c, 0, 0, 0);
      }
      #pragma unroll
      for (int r = 0; r < 4; ++r) {
        unsigned keyu = mono(fmaf(-2.f, c[r], sqv[cf]));
        if (keyu <= th[r]) {
          int row = mrow + l4 * 4 + r;
          int pos = atomicAdd(&CNT[row], 1);
          if (pos < QCAP) QU[row][pos] = (ushort)(n0 + ccol + cf * 16 + c15);
        }
      }
    }
  }

  // ================= pad + dump queues =================
  __syncthreads();
  for (int i = t; i < 32 * QCAP; i += 256) {
    int row = i / QCAP, s2 = i % QCAP;
    int c2 = CNT[row]; if (c2 > QCAP) c2 = QCAP;
    ushort v = (s2 < c2) ? QU[row][s2] : (ushort)0xFFFFu;
    cand[((size_t)(b * NPTS + row0 + row) * 2 + seg) * QCAP + s2] = v;
  }
}

// ---------- exact f64 re-rank of up to 80 candidates, wave per point ----------
__global__ void refine_kernel(const float* __restrict__ pct, const ushort* __restrict__ cand,
                              int* __restrict__ knn, float* __restrict__ idxf) {
  int gw = (blockIdx.x * 256 + threadIdx.x) >> 6;  // 0..16383
  int lane = threadIdx.x & 63;
  int b = gw >> 13, n = gw & (NPTS - 1);
  const float* pcb = pct + (size_t)b * NPTS * 64;
  const ushort* cb = cand + (size_t)gw * (2 * QCAP);
  const float* qp = pcb + (size_t)n * 64;

  unsigned ciA = cb[lane];
  unsigned ciB = (lane < 16) ? (unsigned)cb[64 + lane] : 0xFFFFu;
  double dA = __builtin_inf(), dB = __builtin_inf();
  if (ciA != 0xFFFFu) {
    const float* cp = pcb + (size_t)ciA * 64;
    double s = 0.0;
    #pragma unroll
    for (int u = 0; u < 16; ++u) {
      f32x4 cv = *(const f32x4*)(cp + u * 4);
      f32x4 qv = *(const f32x4*)(qp + u * 4);
      #pragma unroll
      for (int e = 0; e < 4; ++e) {
        double diff = (double)cv[e] - (double)qv[e];
        s = fma(diff, diff, s);
      }
    }
    dA = s;
  }
  if (ciB != 0xFFFFu) {
    const float* cp = pcb + (size_t)ciB * 64;
    double s = 0.0;
    #pragma unroll
    for (int u = 0; u < 16; ++u) {
      f32x4 cv = *(const f32x4*)(cp + u * 4);
      f32x4 qv = *(const f32x4*)(qp + u * 4);
      #pragma unroll
      for (int e = 0; e < 4; ++e) {
        double diff = (double)cv[e] - (double)qv[e];
        s = fma(diff, diff, s);
      }
    }
    dB = s;
  }

  int rA = 0, rB = 0;
  for (int j = 0; j < 64; ++j) {
    double dk = __shfl(dA, j);
    unsigned ik = (unsigned)__shfl((int)ciA, j);
    rA += ((dk < dA) || (dk == dA && ik < ciA)) ? 1 : 0;
    rB += ((dk < dB) || (dk == dB && ik < ciB)) ? 1 : 0;
  }
  for (int j = 0; j < 16; ++j) {
    double dk = __shfl(dB, j);
    unsigned ik = (unsigned)__shfl((int)ciB, j);
    rA += ((dk < dA) || (dk == dA && ik < ciA)) ? 1 : 0;
    rB += ((dk < dB) || (dk == dB && ik < ciB)) ? 1 : 0;
  }
  if (ciA != 0xFFFFu && rA < KOUT) {
    size_t o = ((size_t)b * KOUT + rA) * NPTS + n;
    knn[o] = (int)ciA;
    idxf[o] = (float)ciA;
  }
  if (lane < 16 && ciB != 0xFFFFu && rB < KOUT) {
    size_t o = ((size_t)b * KOUT + rB) * NPTS + n;
    knn[o] = (int)ciB;
    idxf[o] = (float)ciB;
  }
}

// ---------- edge features: out [B][128][17][N] ----------
__global__ void edge_kernel(const float* __restrict__ pc, const int* __restrict__ knn,
                            float* __restrict__ out) {
  int n = blockIdx.x * 256 + threadIdx.x;
  int k = blockIdx.y;
  int z = blockIdx.z;
  int b = z >> 6, c = z & 63;
  int nb = knn[((size_t)b * KOUT + k) * NPTS + n];
  const float* row = pc + ((size_t)b * DIM + c) * NPTS;
  float central = row[n];
  float nbrv = row[nb];
  size_t base = (((size_t)b * 2 * DIM + c) * KOUT + k) * NPTS + n;
  out[base] = central;
  out[base + (size_t)DIM * KOUT * NPTS] = nbrv - central;
}

extern "C" void kernel_launch(void* const* d_in, const int* in_sizes, int n_in,
                              void* d_out, int out_size, void* d_ws, size_t ws_size,
                              hipStream_t stream) {
  const float* pc = (const float*)d_in[0];
  float* out = (float*)d_out;
  char* ws = (char*)d_ws;
  ushort* phl = (ushort*)ws;                                     // 4 MB
  float* pct  = (float*)(ws + (size_t)4 * 1024 * 1024);          // 4 MB
  float* sq   = (float*)(ws + (size_t)8 * 1024 * 1024);          // 64 KB
  ushort* cand = (ushort*)(ws + (size_t)8 * 1024 * 1024 + 65536);          // 2.62 MB
  int* knn    = (int*)(ws + (size_t)8 * 1024 * 1024 + 65536 + (size_t)16384 * 2 * QCAP * 2);

  float* idxf = out + (size_t)BATCH * 2 * DIM * KOUT * NPTS;

  prep_kernel<<<512, 256, 0, stream>>>(pc, phl, pct, sq);
  knn_kernel<<<1024, 256, 0, stream>>>(phl, sq, cand);
  refine_kernel<<<4096, 256, 0, stream>>>(pct, cand, knn, idxf);
  edge_kernel<<<dim3(NPTS / 256, KOUT, BATCH * DIM), 256, 0, stream>>>(pc, knn, out);
}

// Round 6
// 244.930 us; speedup vs baseline: 9.8125x; 1.0418x over previous
//
#include <hip/hip_runtime.h>

#define NPTS 8192
#define DIM 64
#define BATCH 2
#define KOUT 17
#define QCAP 40      // queue capacity per (row, seg)
#define THRANK 21    // theta = 22nd smallest of the 64-subset

typedef float f32x4 __attribute__((ext_vector_type(4)));
typedef short short8 __attribute__((ext_vector_type(8)));
typedef unsigned int uint4v __attribute__((ext_vector_type(4)));

__device__ __forceinline__ void gload16(const void* g, void* lds) {
  __builtin_amdgcn_global_load_lds((const __attribute__((address_space(1))) void*)g,
                                   (__attribute__((address_space(3))) void*)lds, 16, 0, 0);
}

// ---------- prep: permuted hi/lo bf16 (phl), contiguous f32 (pct), 0.5*|x|^2 ----------
__global__ __launch_bounds__(256)
void prep_kernel(const float* __restrict__ pc, ushort* __restrict__ phl,
                 float* __restrict__ pct, float* __restrict__ sq) {
  __shared__ double psum[256];
  int t = threadIdx.x;
  int u = t >> 5;           // 0..7  (dims u*8 .. u*8+7)
  int p = t & 31;           // 0..31 (point within block)
  int i = blockIdx.x * 32 + p;   // 0..16383
  int b = i >> 13, n = i & (NPTS - 1);
  const float* g = pc + (size_t)b * DIM * NPTS + n;

  float x[8];
  short8 hv, lv;
  double s = 0.0;
  #pragma unroll
  for (int e = 0; e < 8; ++e) {
    x[e] = g[(size_t)(u * 8 + e) * NPTS];
    s += (double)x[e] * (double)x[e];
    unsigned uu = __float_as_uint(x[e]);
    unsigned r = uu + (0x7fffu + ((uu >> 16) & 1));
    unsigned hi = r >> 16;                       // bf16 RNE
    float xl = x[e] - __uint_as_float(hi << 16);
    unsigned ul = __float_as_uint(xl);
    unsigned rl = ul + (0x7fffu + ((ul >> 16) & 1));
    hv[e] = (short)(hi & 0xffffu);
    lv[e] = (short)((rl >> 16) & 0xffffu);
  }
  int slot = u ^ (n & 7);
  ushort* ph = phl + (size_t)i * 128;
  *(short8*)(ph + slot * 8) = hv;
  *(short8*)(ph + 64 + slot * 8) = lv;
  f32x4 v0 = {x[0], x[1], x[2], x[3]}, v1 = {x[4], x[5], x[6], x[7]};
  *(f32x4*)(pct + (size_t)i * 64 + u * 8) = v0;
  *(f32x4*)(pct + (size_t)i * 64 + u * 8 + 4) = v1;

  psum[u * 32 + p] = s;
  __syncthreads();
  if (t < 32) {
    double acc = 0.0;
    #pragma unroll
    for (int uu = 0; uu < 8; ++uu) acc += psum[uu * 32 + t];
    sq[blockIdx.x * 32 + t] = (float)(0.5 * acc);   // store HALF |x|^2
  }
}

// ---------- two-pass MFMA distance + theta-filter collect ----------
// 1024 blocks x 256 threads; block = (b, seg, rowgroup): 32 rows x 4096 cols (32 tiles of 128).
// key(row,col) = 0.5*|col|^2 - <row,col>  (same order as squared distance)
__global__ __launch_bounds__(256, 4)
void knn_kernel(const ushort* __restrict__ phl, const float* __restrict__ sq,
                ushort* __restrict__ cand) {
  __shared__ ushort Bt[128 * 128];  // 32 KB; aliased as KT[32][64] between passes
  __shared__ float TH[32];
  __shared__ int CNT[32];
  __shared__ ushort QU[32][QCAP];

  int t = threadIdx.x;
  int lane = t & 63;
  int w = t >> 6;
  int b = blockIdx.x >> 9;
  int seg = (blockIdx.x >> 8) & 1;
  int row0 = (blockIdx.x & 255) * 32;
  const ushort* pb = phl + (size_t)b * NPTS * 128;
  const float* sqb = sq + b * NPTS;

  int c15 = lane & 15, l4 = lane >> 4;
  int mrow = (w & 1) * 16;
  int ccol = (w >> 1) * 64;
  int hh = w >> 1;

  // A fragments from global (pre-permuted layout), once; SIGN-FLIPPED (exact)
  short8 a[2][2];
  {
    int n = row0 + mrow + c15;
    const ushort* pr = pb + (size_t)n * 128;
    #pragma unroll
    for (int kk = 0; kk < 2; ++kk) {
      int slot = (kk * 4 + l4) ^ (n & 7);
      a[0][kk] = *(const short8*)(pr + slot * 8);
      a[1][kk] = *(const short8*)(pr + 64 + slot * 8);
    }
    #pragma unroll
    for (int hl = 0; hl < 2; ++hl)
      #pragma unroll
      for (int kk = 0; kk < 2; ++kk) {
        uint4v uv = *(uint4v*)&a[hl][kk];
        uv ^= 0x80008000u;
        *(uint4v*)&a[hl][kk] = uv;
      }
  }

  // ================= PASS A: per-lane top-2 keys per owned row =================
  float k1[4], k2[4];
  #pragma unroll
  for (int r = 0; r < 4; ++r) { k1[r] = __builtin_inff(); k2[r] = __builtin_inff(); }

  for (int tile = 0; tile < 32; ++tile) {
    int n0 = (seg * 32 + tile) * 128;
    __syncthreads();
    #pragma unroll
    for (int j = 0; j < 8; ++j) {
      const ushort* src = pb + (size_t)(n0 + w * 32 + j * 4 + (lane >> 4)) * 128 + (lane & 15) * 8;
      gload16(src, Bt + (w * 32 + j * 4) * 128);
    }
    float sqv[4];
    #pragma unroll
    for (int cf = 0; cf < 4; ++cf) sqv[cf] = sqb[n0 + ccol + cf * 16 + c15];
    __syncthreads();

    #pragma unroll
    for (int cf = 0; cf < 4; ++cf) {
      int lc = ccol + cf * 16 + c15;
      const ushort* bp = Bt + lc * 128;
      f32x4 c = {sqv[cf], sqv[cf], sqv[cf], sqv[cf]};   // C-init = 0.5*|col|^2
      #pragma unroll
      for (int kk = 0; kk < 2; ++kk) {
        int so = ((kk * 4 + l4) ^ (lc & 7)) * 8;
        short8 bh = *(const short8*)(bp + so);
        short8 bl = *(const short8*)(bp + 64 + so);
        c = __builtin_amdgcn_mfma_f32_16x16x32_bf16(a[0][kk], bh, c, 0, 0, 0);
        c = __builtin_amdgcn_mfma_f32_16x16x32_bf16(a[0][kk], bl, c, 0, 0, 0);
        c = __builtin_amdgcn_mfma_f32_16x16x32_bf16(a[1][kk], bh, c, 0, 0, 0);
      }
      #pragma unroll
      for (int r = 0; r < 4; ++r) {
        float key = c[r];
        k2[r] = __builtin_amdgcn_fmed3f(key, k1[r], k2[r]);  // new 2nd-smallest
        k1[r] = fminf(key, k1[r]);
      }
    }
  }

  // ================= theta per row = 22nd smallest of 64-subset =================
  __syncthreads();
  float* KT = (float*)Bt;   // [32][64]
  #pragma unroll
  for (int r = 0; r < 4; ++r) {
    int row = mrow + l4 * 4 + r;
    KT[row * 64 + hh * 32 + c15 * 2] = k1[r];
    KT[row * 64 + hh * 32 + c15 * 2 + 1] = k2[r];
  }
  __syncthreads();
  {
    int row = t >> 3;
    int j0 = (t & 7) * 8;
    const f32x4* vr4 = (const f32x4*)(KT + row * 64);
    float vj[8];
    *(f32x4*)vj = vr4[(t & 7) * 2];
    *(f32x4*)(vj + 4) = vr4[(t & 7) * 2 + 1];
    int rank[8];
    #pragma unroll
    for (int jj = 0; jj < 8; ++jj) rank[jj] = 0;
    for (int m4 = 0; m4 < 16; ++m4) {
      f32x4 vm = vr4[m4];
      #pragma unroll
      for (int e = 0; e < 4; ++e) {
        int m = m4 * 4 + e;
        float ve = vm[e];
        #pragma unroll
        for (int jj = 0; jj < 8; ++jj)
          rank[jj] += (ve < vj[jj] || (ve == vj[jj] && m < j0 + jj)) ? 1 : 0;
      }
    }
    #pragma unroll
    for (int jj = 0; jj < 8; ++jj)
      if (rank[jj] == THRANK) TH[row] = vj[jj];
    if (t < 32) CNT[t] = 0;
  }
  __syncthreads();
  float th[4];
  #pragma unroll
  for (int r = 0; r < 4; ++r) th[r] = TH[mrow + l4 * 4 + r];

  // ================= PASS B: recompute + collect key<=theta =================
  for (int tile = 0; tile < 32; ++tile) {
    int n0 = (seg * 32 + tile) * 128;
    __syncthreads();
    #pragma unroll
    for (int j = 0; j < 8; ++j) {
      const ushort* src = pb + (size_t)(n0 + w * 32 + j * 4 + (lane >> 4)) * 128 + (lane & 15) * 8;
      gload16(src, Bt + (w * 32 + j * 4) * 128);
    }
    float sqv[4];
    #pragma unroll
    for (int cf = 0; cf < 4; ++cf) sqv[cf] = sqb[n0 + ccol + cf * 16 + c15];
    __syncthreads();

    #pragma unroll
    for (int cf = 0; cf < 4; ++cf) {
      int lc = ccol + cf * 16 + c15;
      const ushort* bp = Bt + lc * 128;
      f32x4 c = {sqv[cf], sqv[cf], sqv[cf], sqv[cf]};
      #pragma unroll
      for (int kk = 0; kk < 2; ++kk) {
        int so = ((kk * 4 + l4) ^ (lc & 7)) * 8;
        short8 bh = *(const short8*)(bp + so);
        short8 bl = *(const short8*)(bp + 64 + so);
        c = __builtin_amdgcn_mfma_f32_16x16x32_bf16(a[0][kk], bh, c, 0, 0, 0);
        c = __builtin_amdgcn_mfma_f32_16x16x32_bf16(a[0][kk], bl, c, 0, 0, 0);
        c = __builtin_amdgcn_mfma_f32_16x16x32_bf16(a[1][kk], bh, c, 0, 0, 0);
      }
      #pragma unroll
      for (int r = 0; r < 4; ++r) {
        if (c[r] <= th[r]) {
          int row = mrow + l4 * 4 + r;
          int pos = atomicAdd(&CNT[row], 1);
          if (pos < QCAP) QU[row][pos] = (ushort)(n0 + ccol + cf * 16 + c15);
        }
      }
    }
  }

  // ================= pad + dump queues =================
  __syncthreads();
  for (int i = t; i < 32 * QCAP; i += 256) {
    int row = i / QCAP, s2 = i % QCAP;
    int c2 = CNT[row]; if (c2 > QCAP) c2 = QCAP;
    ushort v = (s2 < c2) ? QU[row][s2] : (ushort)0xFFFFu;
    cand[((size_t)(b * NPTS + row0 + row) * 2 + seg) * QCAP + s2] = v;
  }
}

// ---------- exact f64 re-rank of up to 80 candidates, wave per point ----------
__global__ void refine_kernel(const float* __restrict__ pct, const ushort* __restrict__ cand,
                              int* __restrict__ knn, float* __restrict__ idxf) {
  int gw = (blockIdx.x * 256 + threadIdx.x) >> 6;  // 0..16383
  int lane = threadIdx.x & 63;
  int b = gw >> 13, n = gw & (NPTS - 1);
  const float* pcb = pct + (size_t)b * NPTS * 64;
  const ushort* cb = cand + (size_t)gw * (2 * QCAP);
  const float* qp = pcb + (size_t)n * 64;

  unsigned ciA = cb[lane];
  unsigned ciB = (lane < 16) ? (unsigned)cb[64 + lane] : 0xFFFFu;
  double dA = __builtin_inf(), dB = __builtin_inf();
  if (ciA != 0xFFFFu) {
    const float* cp = pcb + (size_t)ciA * 64;
    double s = 0.0;
    #pragma unroll
    for (int u = 0; u < 16; ++u) {
      f32x4 cv = *(const f32x4*)(cp + u * 4);
      f32x4 qv = *(const f32x4*)(qp + u * 4);
      #pragma unroll
      for (int e = 0; e < 4; ++e) {
        double diff = (double)cv[e] - (double)qv[e];
        s = fma(diff, diff, s);
      }
    }
    dA = s;
  }
  if (ciB != 0xFFFFu) {
    const float* cp = pcb + (size_t)ciB * 64;
    double s = 0.0;
    #pragma unroll
    for (int u = 0; u < 16; ++u) {
      f32x4 cv = *(const f32x4*)(cp + u * 4);
      f32x4 qv = *(const f32x4*)(qp + u * 4);
      #pragma unroll
      for (int e = 0; e < 4; ++e) {
        double diff = (double)cv[e] - (double)qv[e];
        s = fma(diff, diff, s);
      }
    }
    dB = s;
  }

  int rA = 0, rB = 0;
  for (int j = 0; j < 64; ++j) {
    double dk = __shfl(dA, j);
    unsigned ik = (unsigned)__shfl((int)ciA, j);
    rA += ((dk < dA) || (dk == dA && ik < ciA)) ? 1 : 0;
    rB += ((dk < dB) || (dk == dB && ik < ciB)) ? 1 : 0;
  }
  for (int j = 0; j < 16; ++j) {
    double dk = __shfl(dB, j);
    unsigned ik = (unsigned)__shfl((int)ciB, j);
    rA += ((dk < dA) || (dk == dA && ik < ciA)) ? 1 : 0;
    rB += ((dk < dB) || (dk == dB && ik < ciB)) ? 1 : 0;
  }
  if (ciA != 0xFFFFu && rA < KOUT) {
    size_t o = ((size_t)b * KOUT + rA) * NPTS + n;
    knn[o] = (int)ciA;
    idxf[o] = (float)ciA;
  }
  if (lane < 16 && ciB != 0xFFFFu && rB < KOUT) {
    size_t o = ((size_t)b * KOUT + rB) * NPTS + n;
    knn[o] = (int)ciB;
    idxf[o] = (float)ciB;
  }
}

// ---------- edge features: out [B][128][17][N]; block = (n-chunk, b*64+c), k-loop inside ----------
__global__ __launch_bounds__(256)
void edge_kernel(const float* __restrict__ pc, const int* __restrict__ knn,
                 float* __restrict__ out) {
  int n = blockIdx.x * 256 + threadIdx.x;
  int z = blockIdx.y;
  int b = z >> 6, c = z & 63;
  const float* row = pc + ((size_t)b * DIM + c) * NPTS;
  float central = row[n];
  size_t base = (((size_t)b * 2 * DIM + c) * KOUT) * NPTS + n;
  const int* kb = knn + (size_t)b * KOUT * NPTS + n;
  #pragma unroll
  for (int k = 0; k < KOUT; ++k) {
    int nb = kb[(size_t)k * NPTS];
    float nbrv = row[nb];
    out[base + (size_t)k * NPTS] = central;
    out[base + (size_t)(DIM * KOUT + k) * NPTS] = nbrv - central;
  }
}

extern "C" void kernel_launch(void* const* d_in, const int* in_sizes, int n_in,
                              void* d_out, int out_size, void* d_ws, size_t ws_size,
                              hipStream_t stream) {
  const float* pc = (const float*)d_in[0];
  float* out = (float*)d_out;
  char* ws = (char*)d_ws;
  ushort* phl = (ushort*)ws;                                     // 4 MB
  float* pct  = (float*)(ws + (size_t)4 * 1024 * 1024);          // 4 MB
  float* sq   = (float*)(ws + (size_t)8 * 1024 * 1024);          // 64 KB
  ushort* cand = (ushort*)(ws + (size_t)8 * 1024 * 1024 + 65536);          // 2.62 MB
  int* knn    = (int*)(ws + (size_t)8 * 1024 * 1024 + 65536 + (size_t)16384 * 2 * QCAP * 2);

  float* idxf = out + (size_t)BATCH * 2 * DIM * KOUT * NPTS;

  prep_kernel<<<512, 256, 0, stream>>>(pc, phl, pct, sq);
  knn_kernel<<<1024, 256, 0, stream>>>(phl, sq, cand);
  refine_kernel<<<4096, 256, 0, stream>>>(pct, cand, knn, idxf);
  edge_kernel<<<dim3(NPTS / 256, BATCH * DIM), 256, 0, stream>>>(pc, knn, out);
}